// Round 8
// baseline (249.448 us; speedup 1.0000x reference)
//
#include <hip/hip_runtime.h>
#include <hip/hip_bf16.h>

// R8 = DIAGNOSTIC ROUND. Correct output produced by main_full (runs last).
// probe_mem (rep=8) and probe_gemm (rep=2) write d_out earlier and are
// overwritten; they exist to appear in the rocprof top-5 with separable
// durations, bisecting the 93us mystery of R6's structure:
//   probe_mem  = stage + barriers + epilogue          (memory skeleton)
//   probe_gemm = + MFMA GEMM + scale + pack           (no zdot, no prefix)
//   main_full  = + zdot + causal prefix               (R6 verbatim, correct)

#define B_  16
#define L_  4096
#define H_  256
#define M_  (B_*L_)
#define CH  64
#define CHROWS 64
#define BM 64

typedef short short4v __attribute__((ext_vector_type(4)));
typedef short short8  __attribute__((ext_vector_type(8)));
typedef float f32x4   __attribute__((ext_vector_type(4)));

__device__ __forceinline__ unsigned short f2bf(float f) {
  unsigned int u = __builtin_bit_cast(unsigned int, f);
  u += 0x7fffu + ((u >> 16) & 1u);
  return (unsigned short)(u >> 16);
}
__device__ __forceinline__ float bf2f(unsigned short s) {
  return __builtin_bit_cast(float, ((unsigned int)s) << 16);
}

// ---------------- K1: W = Wo @ Wv -> bf16 [H][H] ----------------
__global__ void fuse_w_kernel(const float* __restrict__ Wv,
                              const float* __restrict__ Wo,
                              unsigned short* __restrict__ Wbf) {
  __shared__ float wo[H_];
  int h = blockIdx.x, t = threadIdx.x;
  wo[t] = Wo[h*H_ + t];
  __syncthreads();
  float acc = 0.f;
  #pragma unroll 8
  for (int m = 0; m < H_; ++m) acc += wo[m] * Wv[m*H_ + t];
  Wbf[h*H_ + t] = f2bf(acc);
}

// ---------------- K2: per-64-row-chunk column sums ----------------
__global__ void partial_kernel(const float* __restrict__ x, float* __restrict__ P) {
  int c = blockIdx.x, b = blockIdx.y, t = threadIdx.x;
  const float* p = x + ((size_t)(b*L_ + c*CHROWS))*H_ + t;
  float s = 0.f;
  #pragma unroll 8
  for (int r = 0; r < CHROWS; ++r) s += p[(size_t)r*H_];
  P[(b*CH + c)*H_ + t] = s;
}

// ------- K3: exclusive scan over 64 chunks via wave shuffle (lane=chunk) -------
__global__ void scan_kernel(const float* __restrict__ P, float* __restrict__ O) {
  int cg = blockIdx.x, b = blockIdx.y;
  int lane = threadIdx.x & 63, w = threadIdx.x >> 6;
  int col = cg*4 + w;
  int idx = (b*CH + lane)*H_ + col;
  float val = P[idx];
  float inc = val, t;
  t = __shfl_up(inc, 1);  if (lane >= 1)  inc += t;
  t = __shfl_up(inc, 2);  if (lane >= 2)  inc += t;
  t = __shfl_up(inc, 4);  if (lane >= 4)  inc += t;
  t = __shfl_up(inc, 8);  if (lane >= 8)  inc += t;
  t = __shfl_up(inc, 16); if (lane >= 16) inc += t;
  t = __shfl_up(inc, 32); if (lane >= 32) inc += t;
  O[idx] = inc - val;
}

// ---------------- probe_mem: stage + barriers + epilogue, rep=8 ----------------
__global__ __launch_bounds__(256) void probe_mem(const float* __restrict__ x,
                                                 float* __restrict__ outp) {
  __shared__ __align__(16) char smem[33792];
  const int tid = threadIdx.x;
  const int rowBase = blockIdx.x * BM;
  const float* xb = x + (size_t)rowBase * H_;
  float* ob = outp + (size_t)rowBase * H_;
  #pragma unroll 1
  for (int rep = 0; rep < 8; ++rep) {
    #pragma unroll
    for (int j = 0; j < 16; ++j) {
      int idx = tid + j*256;
      int row = idx >> 6, col4 = idx & 63;
      float4 v = *(const float4*)(xb + row*H_ + col4*4);
      short4v s;
      s[0] = (short)f2bf(v.x); s[1] = (short)f2bf(v.y);
      s[2] = (short)f2bf(v.z); s[3] = (short)f2bf(v.w);
      *(short4v*)(smem + row*512 + ((col4*8) ^ ((row & 7) << 4))) = s;
    }
    __syncthreads();
    __syncthreads();
    __syncthreads();
    #pragma unroll
    for (int j = 0; j < 16; ++j) {
      int idx = tid + j*256;
      int row = idx >> 6, col4 = idx & 63;
      short4v s = *(const short4v*)(smem + row*512 + ((col4*8) ^ ((row & 7) << 4)));
      float4 xr = *(const float4*)(xb + row*H_ + col4*4);
      float4 o;
      o.x = xr.x + bf2f((unsigned short)s[0]);
      o.y = xr.y + bf2f((unsigned short)s[1]);
      o.z = xr.z + bf2f((unsigned short)s[2]);
      o.w = xr.w + bf2f((unsigned short)s[3]);
      *(float4*)(ob + row*H_ + col4*4) = o;
    }
    __syncthreads();
  }
}

// ------- probe_gemm: stage + GEMM + scale + pack + epilogue, rep=2 -------
__global__ __launch_bounds__(256) void probe_gemm(
    const float* __restrict__ x,
    const unsigned short* __restrict__ Wbf,
    float* __restrict__ outp) {
  __shared__ __align__(16) char smem[33792];
  const int tid = threadIdx.x;
  const int lane = tid & 63, wave = tid >> 6;
  const int lrow = lane & 15, g = lane >> 4;
  const int rowBase = blockIdx.x * BM;
  const float* xb = x + (size_t)rowBase * H_;
  float* ob = outp + (size_t)rowBase * H_;
  #pragma unroll 1
  for (int rep = 0; rep < 2; ++rep) {
    #pragma unroll
    for (int j = 0; j < 16; ++j) {
      int idx = tid + j*256;
      int row = idx >> 6, col4 = idx & 63;
      float4 v = *(const float4*)(xb + row*H_ + col4*4);
      short4v s;
      s[0] = (short)f2bf(v.x); s[1] = (short)f2bf(v.y);
      s[2] = (short)f2bf(v.z); s[3] = (short)f2bf(v.w);
      *(short4v*)(smem + row*512 + ((col4*8) ^ ((row & 7) << 4))) = s;
    }
    __syncthreads();
    f32x4 acc[4][4] = {};
    #pragma unroll
    for (int k0 = 0; k0 < 4; ++k0) {
      #pragma unroll
      for (int ks = 0; ks < 2; ++ks) {
        short8 bfr[4], af[4];
        #pragma unroll
        for (int n = 0; n < 4; ++n) {
          int wrow = wave*64 + n*16 + lrow;
          bfr[n] = *(const short8*)(Wbf + (size_t)wrow*H_ + k0*64 + ks*32 + g*8);
        }
        #pragma unroll
        for (int i = 0; i < 4; ++i) {
          int ar = i*16 + lrow;
          int cb = (k0*128 + ks*64 + g*16) ^ ((ar & 7) << 4);
          af[i] = *(const short8*)(smem + ar*512 + cb);
        }
        #pragma unroll
        for (int i = 0; i < 4; ++i)
          #pragma unroll
          for (int n = 0; n < 4; ++n)
            acc[i][n] = __builtin_amdgcn_mfma_f32_16x16x32_bf16(af[i], bfr[n], acc[i][n], 0, 0, 0);
      }
    }
    // scale only (no prefix, no zdot)
    #pragma unroll
    for (int n = 0; n < 4; ++n)
      #pragma unroll
      for (int i = 0; i < 4; ++i)
        #pragma unroll
        for (int q = 0; q < 4; ++q) {
          int row = rowBase + i*16 + g*4 + q;
          acc[i][n][q] *= 1.0f / (float)((row & (L_-1)) + 1);
        }
    __syncthreads();
    #pragma unroll
    for (int i = 0; i < 4; ++i)
      #pragma unroll
      for (int n = 0; n < 4; ++n)
        #pragma unroll
        for (int q = 0; q < 4; ++q) {
          int row = i*16 + g*4 + q;
          int col = wave*64 + n*16 + lrow;
          *(unsigned short*)(smem + row*512 + ((col*2) ^ ((row & 7) << 4))) =
              f2bf(acc[i][n][q]);
        }
    __syncthreads();
    #pragma unroll
    for (int j = 0; j < 16; ++j) {
      int idx = tid + j*256;
      int row = idx >> 6, col4 = idx & 63;
      short4v s = *(const short4v*)(smem + row*512 + ((col4*8) ^ ((row & 7) << 4)));
      float4 xr = *(const float4*)(xb + row*H_ + col4*4);
      float4 o;
      o.x = xr.x + bf2f((unsigned short)s[0]);
      o.y = xr.y + bf2f((unsigned short)s[1]);
      o.z = xr.z + bf2f((unsigned short)s[2]);
      o.w = xr.w + bf2f((unsigned short)s[3]);
      *(float4*)(ob + row*H_ + col4*4) = o;
    }
    __syncthreads();
  }
}

// ---------------- main_full: R6 kernel verbatim (correct output) ----------------
__global__ __launch_bounds__(256) void main_full(
    const float* __restrict__ x,
    const unsigned short* __restrict__ Wbf,
    const float* __restrict__ Op,
    float* __restrict__ out) {
  __shared__ __align__(16) char smem[33792];
  float* zbuf = (float*)(smem + 32768);

  const int tid = threadIdx.x;
  const int lane = tid & 63, wave = tid >> 6;
  const int rowBase = blockIdx.x * BM;
  const float* xb = x + (size_t)rowBase * H_;

  #pragma unroll
  for (int j = 0; j < 16; ++j) {
    int idx = tid + j*256;
    int row = idx >> 6, col4 = idx & 63;
    float4 v = *(const float4*)(xb + row*H_ + col4*4);
    short4v s;
    s[0] = (short)f2bf(v.x); s[1] = (short)f2bf(v.y);
    s[2] = (short)f2bf(v.z); s[3] = (short)f2bf(v.w);
    *(short4v*)(smem + row*512 + ((col4*8) ^ ((row & 7) << 4))) = s;
  }

  {
    const float* op = Op + (size_t)blockIdx.x * H_;
    const unsigned short* wr = Wbf + (size_t)tid * H_;
    float ze[8] = {0,0,0,0,0,0,0,0};
    #pragma unroll
    for (int kk = 0; kk < 32; ++kk) {
      short8 w8 = *(const short8*)(wr + kk*8);
      #pragma unroll
      for (int e = 0; e < 8; ++e) ze[e] += op[kk*8 + e] * bf2f((unsigned short)w8[e]);
    }
    zbuf[tid] = ((ze[0]+ze[1]) + (ze[2]+ze[3])) + ((ze[4]+ze[5]) + (ze[6]+ze[7]));
  }
  __syncthreads();

  const int lrow = lane & 15, g = lane >> 4;
  f32x4 acc[4][4] = {};
  #pragma unroll
  for (int k0 = 0; k0 < 4; ++k0) {
    #pragma unroll
    for (int ks = 0; ks < 2; ++ks) {
      short8 bfr[4], af[4];
      #pragma unroll
      for (int n = 0; n < 4; ++n) {
        int wrow = wave*64 + n*16 + lrow;
        bfr[n] = *(const short8*)(Wbf + (size_t)wrow*H_ + k0*64 + ks*32 + g*8);
      }
      #pragma unroll
      for (int i = 0; i < 4; ++i) {
        int ar = i*16 + lrow;
        int cb = (k0*128 + ks*64 + g*16) ^ ((ar & 7) << 4);
        af[i] = *(const short8*)(smem + ar*512 + cb);
      }
      #pragma unroll
      for (int i = 0; i < 4; ++i)
        #pragma unroll
        for (int n = 0; n < 4; ++n)
          acc[i][n] = __builtin_amdgcn_mfma_f32_16x16x32_bf16(af[i], bfr[n], acc[i][n], 0, 0, 0);
    }
  }

  #pragma unroll
  for (int n = 0; n < 4; ++n) {
    float base = zbuf[wave*64 + n*16 + lrow];
    float run = 0.f;
    #pragma unroll
    for (int i = 0; i < 4; ++i) {
      f32x4 a = acc[i][n];
      a[1] += a[0]; a[2] += a[1]; a[3] += a[2];
      float Bv = a[3];
      float v = Bv, t;
      t = __shfl_up(v, 16); if (lane >= 16) v += t;
      t = __shfl_up(v, 32); if (lane >= 32) v += t;
      float gex = v - Bv;
      float tot = __shfl(v, lrow + 48);
      float addv = gex + run + base;
      #pragma unroll
      for (int q = 0; q < 4; ++q) {
        int row = rowBase + i*16 + g*4 + q;
        float scale = 1.0f / (float)((row & (L_-1)) + 1);
        a[q] = (a[q] + addv) * scale;
      }
      acc[i][n] = a;
      run += tot;
    }
  }
  __syncthreads();

  #pragma unroll
  for (int i = 0; i < 4; ++i)
    #pragma unroll
    for (int n = 0; n < 4; ++n)
      #pragma unroll
      for (int q = 0; q < 4; ++q) {
        int row = i*16 + g*4 + q;
        int col = wave*64 + n*16 + lrow;
        *(unsigned short*)(smem + row*512 + ((col*2) ^ ((row & 7) << 4))) =
            f2bf(acc[i][n][q]);
      }
  __syncthreads();

  float* ob = out + (size_t)rowBase * H_;
  #pragma unroll
  for (int j = 0; j < 16; ++j) {
    int idx = tid + j*256;
    int row = idx >> 6, col4 = idx & 63;
    short4v s = *(const short4v*)(smem + row*512 + ((col4*8) ^ ((row & 7) << 4)));
    float4 xr = *(const float4*)(xb + row*H_ + col4*4);
    float4 o;
    o.x = xr.x + bf2f((unsigned short)s[0]);
    o.y = xr.y + bf2f((unsigned short)s[1]);
    o.z = xr.z + bf2f((unsigned short)s[2]);
    o.w = xr.w + bf2f((unsigned short)s[3]);
    *(float4*)(ob + row*H_ + col4*4) = o;
  }
}

extern "C" void kernel_launch(void* const* d_in, const int* in_sizes, int n_in,
                              void* d_out, int out_size, void* d_ws, size_t ws_size,
                              hipStream_t stream) {
  const float* x  = (const float*)d_in[0];
  const float* Wv = (const float*)d_in[1];
  const float* Wo = (const float*)d_in[2];
  float* out = (float*)d_out;

  char* ws = (char*)d_ws;
  unsigned short* Wbf = (unsigned short*)ws;                    // 128KB
  float* P  = (float*)(ws + 131072);                            // 1MB
  float* Op = (float*)(ws + 131072 + 1048576);                  // 1MB

  hipLaunchKernelGGL(fuse_w_kernel,  dim3(H_),      dim3(H_),  0, stream, Wv, Wo, Wbf);
  hipLaunchKernelGGL(partial_kernel, dim3(CH, B_),  dim3(H_),  0, stream, x, P);
  hipLaunchKernelGGL(scan_kernel,    dim3(64, B_),  dim3(256), 0, stream, P, Op);
  // probes (outputs overwritten by main_full)
  hipLaunchKernelGGL(probe_mem,      dim3(M_/BM),   dim3(256), 0, stream, x, out);
  hipLaunchKernelGGL(probe_gemm,     dim3(M_/BM),   dim3(256), 0, stream, x, Wbf, out);
  // correct result, last
  hipLaunchKernelGGL(main_full,      dim3(M_/BM),   dim3(256), 0, stream, x, Wbf, Op, out);
}

// Round 9
// 100.194 us; speedup vs baseline: 2.4896x; 2.4896x over previous
//
#include <hip/hip_runtime.h>
#include <hip/hip_bf16.h>

// out = x + T @ (x @ Wv^T @ Wo^T), T causal uniform average. fp32 B=16,L=4096,H=256.
// W = Wo@Wv; S = cumsum(x); out = x + (S@W^T)/(i+1), computed per 64-row block as
// Y = Xbf@W^T (MFMA) -> in-register causal prefix + carry Z[r] (PREcomputed
// Z = Op@W^T, coalesced) -> scale -> f32 LDS transpose -> coalesced epilogue.
// R9 = R4 (best fused shape, 512thr/BM=64) minus zdot (moved to zmat_kernel),
// minus the register-spilling launch_bounds cap.

#define B_  16
#define L_  4096
#define H_  256
#define M_  (B_*L_)
#define CH  64
#define CHROWS 64
#define BM 64

typedef short short4v __attribute__((ext_vector_type(4)));
typedef short short8  __attribute__((ext_vector_type(8)));
typedef float f32x4   __attribute__((ext_vector_type(4)));

__device__ __forceinline__ unsigned short f2bf(float f) {
  unsigned int u = __builtin_bit_cast(unsigned int, f);
  u += 0x7fffu + ((u >> 16) & 1u);
  return (unsigned short)(u >> 16);
}
__device__ __forceinline__ float bf2f(unsigned short s) {
  return __builtin_bit_cast(float, ((unsigned int)s) << 16);
}

// -------- K1: W = Wo @ Wv -> Wbf (bf16 [c][k]) + WbfTf (f32 [k][c]) --------
__global__ void fuse_w_kernel(const float* __restrict__ Wv,
                              const float* __restrict__ Wo,
                              unsigned short* __restrict__ Wbf,
                              float* __restrict__ WbfTf) {
  __shared__ float wo[H_];
  int h = blockIdx.x, t = threadIdx.x;
  wo[t] = Wo[h*H_ + t];
  __syncthreads();
  float acc = 0.f;
  #pragma unroll 8
  for (int m = 0; m < H_; ++m) acc += wo[m] * Wv[m*H_ + t];
  Wbf[h*H_ + t] = f2bf(acc);     // W[h][t], h = output col, t = k
  WbfTf[t*H_ + h] = acc;         // transposed, f32, for zmat
}

// ---------------- K2: per-64-row-chunk column sums ----------------
__global__ void partial_kernel(const float* __restrict__ x, float* __restrict__ P) {
  int c = blockIdx.x, b = blockIdx.y, t = threadIdx.x;
  const float* p = x + ((size_t)(b*L_ + c*CHROWS))*H_ + t;
  float s = 0.f;
  #pragma unroll 8
  for (int r = 0; r < CHROWS; ++r) s += p[(size_t)r*H_];
  P[(b*CH + c)*H_ + t] = s;
}

// ------- K3: exclusive scan over 64 chunks via wave shuffle (lane=chunk) -------
__global__ void scan_kernel(const float* __restrict__ P, float* __restrict__ O) {
  int cg = blockIdx.x, b = blockIdx.y;
  int lane = threadIdx.x & 63, w = threadIdx.x >> 6;
  int col = cg*4 + w;
  int idx = (b*CH + lane)*H_ + col;
  float val = P[idx];
  float inc = val, t;
  t = __shfl_up(inc, 1);  if (lane >= 1)  inc += t;
  t = __shfl_up(inc, 2);  if (lane >= 2)  inc += t;
  t = __shfl_up(inc, 4);  if (lane >= 4)  inc += t;
  t = __shfl_up(inc, 8);  if (lane >= 8)  inc += t;
  t = __shfl_up(inc, 16); if (lane >= 16) inc += t;
  t = __shfl_up(inc, 32); if (lane >= 32) inc += t;
  O[idx] = inc - val;
}

// -------- KZ: Z[r][c] = Op[r] . W[c][.] via coalesced f32 W^T reads --------
// 256 blocks x 256 thr; sub-block r = bid*4 + (tid>>6); lane handles 4 cols.
__global__ void zmat_kernel(const float* __restrict__ Op,
                            const float* __restrict__ WbfTf,
                            float* __restrict__ Z) {
  const int lane = threadIdx.x & 63;
  const int r = blockIdx.x*4 + (threadIdx.x >> 6);
  const float* op = Op + (size_t)r * H_;
  f32x4 a0 = {0,0,0,0}, a1 = {0,0,0,0};
  #pragma unroll 8
  for (int k = 0; k < H_; k += 2) {
    float o0 = op[k], o1 = op[k+1];
    f32x4 w0 = *(const f32x4*)(WbfTf + (size_t)k*H_ + lane*4);
    f32x4 w1 = *(const f32x4*)(WbfTf + (size_t)(k+1)*H_ + lane*4);
    a0 += o0 * w0;
    a1 += o1 * w1;
  }
  *(f32x4*)(Z + (size_t)r*H_ + lane*4) = a0 + a1;
}

// ---------------- main: 1024 blocks x 512 thr (8 waves) ----------------
// Wave w owns cols [w*32, w*32+32), all 64 rows.
// LDS: [0,32768) X bf16 [64][256] XOR-swizzled (dead after GEMM)
//      [0,66560)  Ytr f32, 64 rows, stride 1040B (reuses X region post-GEMM)
__global__ __launch_bounds__(512) void main_kernel(
    const float* __restrict__ x,
    const unsigned short* __restrict__ Wbf,
    const float* __restrict__ Z,           // [1024][256] carry rows
    float* __restrict__ out) {
  __shared__ __align__(16) char smem[66560];

  const int tid = threadIdx.x;
  const int lane = tid & 63, wave = tid >> 6;
  const int lrow = lane & 15, g = lane >> 4;
  const int rowBase = blockIdx.x * BM;
  const float* xb = x + (size_t)rowBase * H_;

  // ---- carry row (1 line per wave, issued first) ----
  float base[2];
  #pragma unroll
  for (int n = 0; n < 2; ++n)
    base[n] = Z[(size_t)blockIdx.x*H_ + wave*32 + n*16 + lrow];

  // ---- stage X tile: 8 coalesced float4 loads, kept for residual ----
  float4 xk[8];
  #pragma unroll
  for (int j = 0; j < 8; ++j)
    xk[j] = *(const float4*)(xb + (j*8 + wave)*H_ + lane*4);

  // ---- convert + swizzled LDS write of X tile ----
  #pragma unroll
  for (int j = 0; j < 8; ++j) {
    int r = j*8 + wave;
    short4v s;
    s[0] = (short)f2bf(xk[j].x); s[1] = (short)f2bf(xk[j].y);
    s[2] = (short)f2bf(xk[j].z); s[3] = (short)f2bf(xk[j].w);
    *(short4v*)(smem + r*512 + ((lane*8) ^ ((r & 7) << 4))) = s;
  }
  __syncthreads();

  // ---- GEMM: acc = Xbf @ W^T. Wave tile 64 rows x 32 cols ----
  f32x4 acc[4][2] = {};
  #pragma unroll
  for (int k0 = 0; k0 < 4; ++k0) {
    #pragma unroll
    for (int ks = 0; ks < 2; ++ks) {
      short8 bfr[2], af[4];
      #pragma unroll
      for (int n = 0; n < 2; ++n) {
        int wrow = wave*32 + n*16 + lrow;
        bfr[n] = *(const short8*)(Wbf + (size_t)wrow*H_ + k0*64 + ks*32 + g*8);
      }
      #pragma unroll
      for (int i = 0; i < 4; ++i) {
        int ar = i*16 + lrow;
        int cb = (k0*128 + ks*64 + g*16) ^ ((ar & 7) << 4);
        af[i] = *(const short8*)(smem + ar*512 + cb);
      }
      #pragma unroll
      for (int i = 0; i < 4; ++i)
        #pragma unroll
        for (int n = 0; n < 2; ++n)
          acc[i][n] = __builtin_amdgcn_mfma_f32_16x16x32_bf16(af[i], bfr[n], acc[i][n], 0, 0, 0);
    }
  }

  // ---- causal prefix over 64 rows + carry + scale ----
  #pragma unroll
  for (int n = 0; n < 2; ++n) {
    float run = 0.f;
    #pragma unroll
    for (int i = 0; i < 4; ++i) {
      f32x4 a = acc[i][n];
      a[1] += a[0]; a[2] += a[1]; a[3] += a[2];     // q-inclusive
      float Bv = a[3];
      float v = Bv, t;
      t = __shfl_up(v, 16); if (lane >= 16) v += t;
      t = __shfl_up(v, 32); if (lane >= 32) v += t; // g-inclusive of 4-blocks
      float gex = v - Bv;
      float tot = __shfl(v, lrow + 48);             // 16-row column total
      float addv = gex + run + base[n];
      #pragma unroll
      for (int q = 0; q < 4; ++q) {
        int row = rowBase + i*16 + g*4 + q;
        float scale = 1.0f / (float)((row & (L_-1)) + 1);
        a[q] = (a[q] + addv) * scale;
      }
      acc[i][n] = a;
      run += tot;
    }
  }
  __syncthreads();                                   // X-LDS dead; reuse for Ytr

  // ---- transpose Y through LDS (stride 1040B) ----
  #pragma unroll
  for (int i = 0; i < 4; ++i)
    #pragma unroll
    for (int n = 0; n < 2; ++n)
      #pragma unroll
      for (int q = 0; q < 4; ++q) {
        int row = i*16 + g*4 + q, col = wave*32 + n*16 + lrow;
        *(float*)(smem + row*1040 + col*4) = acc[i][n][q];
      }
  __syncthreads();

  // ---- coalesced epilogue: out = xk + Ytr ----
  float* ob = out + (size_t)rowBase * H_;
  #pragma unroll
  for (int j = 0; j < 8; ++j) {
    int r = j*8 + wave;
    f32x4 y = *(const f32x4*)(smem + r*1040 + lane*16);
    float4 o;
    o.x = xk[j].x + y[0]; o.y = xk[j].y + y[1];
    o.z = xk[j].z + y[2]; o.w = xk[j].w + y[3];
    *(float4*)(ob + r*H_ + lane*4) = o;
  }
}

extern "C" void kernel_launch(void* const* d_in, const int* in_sizes, int n_in,
                              void* d_out, int out_size, void* d_ws, size_t ws_size,
                              hipStream_t stream) {
  const float* x  = (const float*)d_in[0];
  const float* Wv = (const float*)d_in[1];
  const float* Wo = (const float*)d_in[2];
  float* out = (float*)d_out;

  char* ws = (char*)d_ws;
  unsigned short* Wbf = (unsigned short*)ws;                  // 128KB @0
  float* WbfTf = (float*)(ws + 131072);                       // 256KB
  float* P  = (float*)(ws + 131072 + 262144);                 // 1MB
  float* Op = (float*)(ws + 131072 + 262144 + 1048576);       // 1MB
  float* Z  = (float*)(ws + 131072 + 262144 + 2097152);       // 1MB

  hipLaunchKernelGGL(fuse_w_kernel,  dim3(H_),     dim3(H_),  0, stream, Wv, Wo, Wbf, WbfTf);
  hipLaunchKernelGGL(partial_kernel, dim3(CH, B_), dim3(H_),  0, stream, x, P);
  hipLaunchKernelGGL(scan_kernel,    dim3(64, B_), dim3(256), 0, stream, P, Op);
  hipLaunchKernelGGL(zmat_kernel,    dim3(256),    dim3(256), 0, stream, Op, WbfTf, Z);
  hipLaunchKernelGGL(main_kernel,    dim3(M_/BM),  dim3(512), 0, stream, x, Wbf, Z, out);
}